// Round 1
// baseline (5522.699 us; speedup 1.0000x reference)
//
#include <hip/hip_runtime.h>
#include <cstdint>

#define NPTS 2048
#define BATCH 8
#define KNN 40

__device__ __forceinline__ float lrelu(float v){ return fmaxf(v, 0.2f*v); }

// ---------------- generic transpose: dst[c*R+r] = src[r*ld+off+c] ----------------
__global__ void transpose_kernel(const float* __restrict__ src, float* __restrict__ dst,
                                 int R, int C, int ld, int off){
  int i = blockIdx.x*256 + threadIdx.x;
  if (i < R*C){ int r = i / C, c = i % C; dst[c*R + r] = src[r*ld + off + c]; }
}

// ---------------- squared norms per point, rows layout (B,C,N) ----------------
__global__ void norms_kernel(const float* __restrict__ x, float* __restrict__ xx, int C, int N){
  int b = blockIdx.y; int n = blockIdx.x*256 + threadIdx.x;
  const float* xb = x + (size_t)b*C*N;
  float s = 0.f;
  for (int c=0;c<C;c++){ float v = xb[(size_t)c*N + n]; s += v*v; }
  xx[(size_t)b*N + n] = s;
}

// ---------------- fused dist + top-K per point ----------------
// block = 256 threads, one block per (b,n). dist = 2<xn,xm> - |xn|^2 - |xm|^2.
// tie-break: larger value first, then lower index (matches lax.top_k).
template<int C>
__global__ __launch_bounds__(256) void knn_kernel(
    const float* __restrict__ xrows, const float* __restrict__ ctrT, int ctrLd, int ctrOff,
    const float* __restrict__ xx, int* __restrict__ idxout, int N){
  const int b = blockIdx.y, n = blockIdx.x, tid = threadIdx.x;
  const float* xb = xrows + (size_t)b*C*N;
  __shared__ float ctr[C];
  if (C == 3){ if (tid < 3) ctr[tid] = xb[(size_t)tid*N + n]; }
  else       { if (tid < C) ctr[tid] = ctrT[((size_t)b*N + n)*ctrLd + ctrOff + tid]; }
  __syncthreads();
  float acc[8];
#pragma unroll
  for (int j=0;j<8;j++) acc[j]=0.f;
  for (int c=0;c<C;c++){
    float xc = ctr[c];
    const float* row = xb + (size_t)c*N;
#pragma unroll
    for (int j=0;j<8;j++) acc[j] = fmaf(xc, row[j*256+tid], acc[j]);
  }
  const float* xxb = xx + (size_t)b*N;
  float xxn = xxb[n];
  float dist[8];
#pragma unroll
  for (int j=0;j<8;j++) dist[j] = 2.f*acc[j] - xxn - xxb[j*256+tid];
  unsigned mask = 0xFFu;
  __shared__ float swv[4]; __shared__ int swi[4]; __shared__ int winner;
  int* out = idxout + ((size_t)b*N + n)*KNN;
  for (int r=0;r<KNN;r++){
    float bv = -__builtin_inff(); int bi = 0x7FFFFFFF;
#pragma unroll
    for (int j=0;j<8;j++){
      if (mask & (1u<<j)){
        float v = dist[j]; int m = j*256 + tid;
        if (v > bv || (v == bv && m < bi)){ bv = v; bi = m; }
      }
    }
#pragma unroll
    for (int off=32; off>=1; off>>=1){
      float ov = __shfl_xor(bv, off);
      int   oi = __shfl_xor(bi, off);
      if (ov > bv || (ov == bv && oi < bi)){ bv = ov; bi = oi; }
    }
    if ((tid & 63) == 0){ swv[tid>>6] = bv; swi[tid>>6] = bi; }
    __syncthreads();
    if (tid == 0){
      float v0 = swv[0]; int i0 = swi[0];
#pragma unroll
      for (int q=1;q<4;q++){ if (swv[q] > v0 || (swv[q] == v0 && swi[q] < i0)){ v0 = swv[q]; i0 = swi[q]; } }
      winner = i0; out[r] = i0;
    }
    __syncthreads();
    int wi = winner;
    if ((wi & 255) == tid) mask &= ~(1u << (wi >> 8));
  }
}

// ---------------- edge conv A (t-path): 3ch -> 6feat -> 64 -> 128, max over k ----------------
// block 256 = 2 points x 128 output channels
__global__ __launch_bounds__(256) void edgeA_kernel(
    const float* __restrict__ x, const int* __restrict__ idx,
    const float* __restrict__ w1, const float* __restrict__ w2,
    float* __restrict__ tT, int N){
  const int p = threadIdx.x>>7, o = threadIdx.x & 127;
  const int b = blockIdx.y, n = blockIdx.x*2 + p;
  __shared__ float w1T[6*64];
  __shared__ float w2T[64*128];
  __shared__ float s1sh[2*64];
  for (int i=threadIdx.x; i<6*64; i+=256){ int oo=i/6, c=i%6; w1T[c*64+oo] = w1[i]; }
  for (int i=threadIdx.x; i<128*64; i+=256){ int oo=i>>6, c=i&63; w2T[c*128+oo] = w2[i]; }
  const float* xb = x + (size_t)b*3*N;
  float c0 = xb[n], c1 = xb[N+n], c2 = xb[2*N+n];
  const int* id = idx + ((size_t)b*N + n)*KNN;
  __syncthreads();
  float base = 0.f;
  if (o < 64)
    base = (w1T[3*64+o]-w1T[0*64+o])*c0 + (w1T[4*64+o]-w1T[1*64+o])*c1 + (w1T[5*64+o]-w1T[2*64+o])*c2;
  float mx = -__builtin_inff();
  for (int k=0;k<KNN;k++){
    int m = id[k];
    float n0v = xb[m], n1v = xb[N+m], n2v = xb[2*N+m];
    if (o < 64){
      float s = base + w1T[o]*n0v + w1T[64+o]*n1v + w1T[128+o]*n2v;
      s1sh[p*64+o] = lrelu(s);
    }
    __syncthreads();
    float s2 = 0.f;
#pragma unroll 8
    for (int c=0;c<64;c++) s2 = fmaf(w2T[c*128+o], s1sh[p*64+c], s2);
    mx = fmaxf(mx, lrelu(s2));
    __syncthreads();
  }
  tT[((size_t)b*N + n)*128 + o] = mx;
}

// ---------------- edge conv B: 3ch -> 6feat -> 64 -> 64, max over k ----------------
// block 256 = 4 points x 64 channels
__global__ __launch_bounds__(256) void edgeB_kernel(
    const float* __restrict__ x, const int* __restrict__ idx,
    const float* __restrict__ w1, const float* __restrict__ w2,
    float* __restrict__ xrowsOut, float* __restrict__ catT, int N){
  const int p = threadIdx.x>>6, o = threadIdx.x & 63;
  const int b = blockIdx.y, n = blockIdx.x*4 + p;
  __shared__ float w1T[6*64];
  __shared__ float w2T[64*64];
  __shared__ float s1sh[4*64];
  for (int i=threadIdx.x;i<6*64;i+=256){ int oo=i/6, c=i%6; w1T[c*64+oo]=w1[i]; }
  for (int i=threadIdx.x;i<64*64;i+=256){ int oo=i>>6, c=i&63; w2T[c*64+oo]=w2[i]; }
  const float* xb = x + (size_t)b*3*N;
  float c0=xb[n], c1=xb[N+n], c2=xb[2*N+n];
  const int* id = idx + ((size_t)b*N+n)*KNN;
  __syncthreads();
  float base = (w1T[3*64+o]-w1T[0*64+o])*c0 + (w1T[4*64+o]-w1T[1*64+o])*c1 + (w1T[5*64+o]-w1T[2*64+o])*c2;
  float mx = -__builtin_inff();
  for (int k=0;k<KNN;k++){
    int m = id[k];
    float s = base + w1T[o]*xb[m] + w1T[64+o]*xb[N+m] + w1T[128+o]*xb[2*N+m];
    s1sh[p*64+o] = lrelu(s);
    __syncthreads();
    float s2=0.f;
#pragma unroll 8
    for (int c=0;c<64;c++) s2 = fmaf(w2T[c*64+o], s1sh[p*64+c], s2);
    mx = fmaxf(mx, lrelu(s2));
    __syncthreads();
  }
  xrowsOut[((size_t)b*64 + o)*N + n] = mx;
  catT[((size_t)b*N + n)*192 + o] = mx;
}

// ---------------- edge conv C: 64ch -> 128feat -> 64 -> 64, max over k ----------------
__global__ __launch_bounds__(256) void edgeC_kernel(
    const float* __restrict__ inT, int inOff, const int* __restrict__ idx,
    const float* __restrict__ w1, const float* __restrict__ w2,
    float* __restrict__ xrowsOut, float* __restrict__ catTOut, int outOff, int N){
  const int p = threadIdx.x>>6, o = threadIdx.x & 63;
  const int b = blockIdx.y, n = blockIdx.x*4 + p;
  __shared__ float w1T[128*64];
  __shared__ float w2T[64*64];
  __shared__ float s1sh[4*64];
  __shared__ float ctr[4*64];
  __shared__ float nbr[4*64];
  for (int i=threadIdx.x;i<128*64;i+=256){ int oo=i>>7, c=i&127; w1T[c*64+oo]=w1[i]; }
  for (int i=threadIdx.x;i<64*64;i+=256){ int oo=i>>6, c=i&63; w2T[c*64+oo]=w2[i]; }
  ctr[p*64+o] = inT[((size_t)b*N+n)*192 + inOff + o];
  const int* id = idx + ((size_t)b*N+n)*KNN;
  __syncthreads();
  float base = 0.f;
#pragma unroll 4
  for (int c=0;c<64;c++) base += (w1T[(64+c)*64+o] - w1T[c*64+o]) * ctr[p*64+c];
  float mx = -__builtin_inff();
  for (int k=0;k<KNN;k++){
    int m = id[k];
    nbr[p*64+o] = inT[((size_t)b*N+m)*192 + inOff + o];
    __syncthreads();
    float s = base;
#pragma unroll 8
    for (int c=0;c<64;c++) s = fmaf(w1T[c*64+o], nbr[p*64+c], s);
    s1sh[p*64+o] = lrelu(s);
    __syncthreads();
    float s2=0.f;
#pragma unroll 8
    for (int c=0;c<64;c++) s2 = fmaf(w2T[c*64+o], s1sh[p*64+c], s2);
    mx = fmaxf(mx, lrelu(s2));
    __syncthreads();
  }
  xrowsOut[((size_t)b*64+o)*N + n] = mx;
  catTOut[((size_t)b*N+n)*192 + outOff + o] = mx;
}

// ---------------- edge conv D: 64ch -> 128feat -> 64 (single conv), max over k ----------------
__global__ __launch_bounds__(256) void edgeD_kernel(
    const float* __restrict__ inT, int inOff, const int* __restrict__ idx,
    const float* __restrict__ w1, float* __restrict__ catTOut, int outOff, int N){
  const int p = threadIdx.x>>6, o = threadIdx.x & 63;
  const int b = blockIdx.y, n = blockIdx.x*4 + p;
  __shared__ float w1T[128*64];
  __shared__ float ctr[4*64];
  __shared__ float nbr[4*64];
  for (int i=threadIdx.x;i<128*64;i+=256){ int oo=i>>7, c=i&127; w1T[c*64+oo]=w1[i]; }
  ctr[p*64+o] = inT[((size_t)b*N+n)*192 + inOff + o];
  const int* id = idx + ((size_t)b*N+n)*KNN;
  __syncthreads();
  float base = 0.f;
#pragma unroll 4
  for (int c=0;c<64;c++) base += (w1T[(64+c)*64+o] - w1T[c*64+o]) * ctr[p*64+c];
  float mx = -__builtin_inff();
  for (int k=0;k<KNN;k++){
    int m = id[k];
    nbr[p*64+o] = inT[((size_t)b*N+m)*192 + inOff + o];
    __syncthreads();
    float s = base;
#pragma unroll 8
    for (int c=0;c<64;c++) s = fmaf(w1T[c*64+o], nbr[p*64+c], s);
    mx = fmaxf(mx, lrelu(s));
    __syncthreads();
  }
  catTOut[((size_t)b*N+n)*192 + outOff + o] = mx;
}

// ---------------- conv1 (1024 outs) + lrelu + max over n-chunk ----------------
// grid (16 o-chunks, 8 n-splits, B); block 256 = 4 n-lanes x 64 o
template<int CIN>
__global__ __launch_bounds__(256) void convmax_kernel(
    const float* __restrict__ inT, const float* __restrict__ wT,
    float* __restrict__ partial, int N){
  const int b = blockIdx.z, oc = blockIdx.x;
  const int o = threadIdx.x & 63, ng = threadIdx.x >> 6;
  __shared__ float wsh[CIN*64];
  __shared__ float insh[4*CIN];
  __shared__ float red[256];
  for (int i=threadIdx.x;i<CIN*64;i+=256) wsh[i] = wT[(size_t)(i>>6)*1024 + oc*64 + (i&63)];
  __syncthreads();
  float mx = -__builtin_inff();
  const int ns = N/8, nbase = blockIdx.y*ns;
  for (int n0=0;n0<ns;n0+=4){
    const float* src = inT + ((size_t)b*N + nbase + n0)*CIN;
    for (int i=threadIdx.x;i<4*CIN;i+=256) insh[i] = src[i];
    __syncthreads();
    float s = 0.f;
#pragma unroll 4
    for (int c=0;c<CIN;c++) s = fmaf(wsh[c*64+o], insh[ng*CIN+c], s);
    mx = fmaxf(mx, lrelu(s));
    __syncthreads();
  }
  red[threadIdx.x] = mx;
  __syncthreads();
  if (ng == 0){
    float v = fmaxf(fmaxf(red[o], red[64+o]), fmaxf(red[128+o], red[192+o]));
    partial[((size_t)b*8 + blockIdx.y)*1024 + oc*64 + o] = v;
  }
}

__global__ void reduce_max_kernel(const float* __restrict__ partial, float* __restrict__ out){
  int b = blockIdx.y; int o = blockIdx.x*256 + threadIdx.x;
  float v = -__builtin_inff();
  for (int s=0;s<8;s++) v = fmaxf(v, partial[((size_t)b*8 + s)*1024 + o]);
  out[(size_t)b*1024 + o] = v;
}

// ---------------- small FC: out[b,o] = act(W[o,:]*in[b,:] + bias[o]) ----------------
__global__ void fc_kernel(const float* __restrict__ in, const float* __restrict__ W,
                          const float* __restrict__ bias, float* __restrict__ out,
                          int CI, int O, int act){
  int b = blockIdx.x;
  __shared__ float insh[1024];
  for (int i=threadIdx.x;i<CI;i+=blockDim.x) insh[i]=in[(size_t)b*CI+i];
  __syncthreads();
  for (int o=threadIdx.x;o<O;o+=blockDim.x){
    float s = bias ? bias[o] : 0.f;
    for (int c=0;c<CI;c++) s = fmaf(W[(size_t)o*CI+c], insh[c], s);
    if (act) s = lrelu(s);
    out[(size_t)b*O+o]=s;
  }
}

// ---------------- x' = T^T x per batch ----------------
__global__ void transform_kernel(const float* __restrict__ x, const float* __restrict__ T9,
                                 float* __restrict__ xp, int N){
  int b = blockIdx.y; int n = blockIdx.x*256 + threadIdx.x;
  const float* t = T9 + (size_t)b*9;
  float x0=x[((size_t)b*3+0)*N+n], x1=x[((size_t)b*3+1)*N+n], x2=x[((size_t)b*3+2)*N+n];
#pragma unroll
  for (int i=0;i<3;i++)
    xp[((size_t)b*3+i)*N+n] = t[i]*x0 + t[3+i]*x1 + t[6+i]*x2;
}

// ---------------- bias1: n-invariant part of h1 (g,lv channels 0..1087) ----------------
__global__ void bias1_kernel(const float* __restrict__ g, const float* __restrict__ lv,
                             const float* __restrict__ h1w, float* __restrict__ bias1){
  int b = blockIdx.x;
  __shared__ float insh[1088];
  for (int i=threadIdx.x;i<1088;i+=256) insh[i] = (i<1024)? g[(size_t)b*1024+i] : lv[(size_t)b*64 + (i-1024)];
  __syncthreads();
  int o = threadIdx.x;
  float s=0.f;
  for (int c=0;c<1088;c++) s = fmaf(h1w[(size_t)o*1280+c], insh[c], s);
  bias1[(size_t)b*256+o]=s;
}

// ---------------- head conv layers: out[b,n,o] = act(sum_c wT[c,o]*in[b,n,c] + bias[b,o]) ----------------
template<int CI, int O, bool ACT>
__global__ __launch_bounds__(256) void conv1_kernel(
    const float* __restrict__ inT, const float* __restrict__ wT,
    const float* __restrict__ bias, float* __restrict__ outT, int N){
  const int b = blockIdx.y, n0 = blockIdx.x*32;
  __shared__ float insh[32*CI];
  const float* src = inT + ((size_t)b*N + n0)*CI;
  for (int i=threadIdx.x;i<32*CI;i+=256) insh[i] = src[i];
  __syncthreads();
  constexpr int NREP = 256/O;
  constexpr int NLOC = 32/NREP;
  const int o = threadIdx.x % O, rep = threadIdx.x / O;
  float acc[NLOC];
#pragma unroll
  for (int t=0;t<NLOC;t++) acc[t]=0.f;
  for (int c=0;c<CI;c++){
    float wv = wT[c*O + o];
#pragma unroll
    for (int t=0;t<NLOC;t++) acc[t] = fmaf(wv, insh[(t*NREP+rep)*CI + c], acc[t]);
  }
  float bv = bias ? bias[(size_t)b*O + o] : 0.f;
#pragma unroll
  for (int t=0;t<NLOC;t++){
    float s = acc[t] + bv;
    if (ACT) s = lrelu(s);
    outT[((size_t)b*N + n0 + t*NREP + rep)*O + o] = s;
  }
}

// ---------------- final layer: 128 -> 50, rows-layout output (B,50,N) ----------------
__global__ __launch_bounds__(256) void conv_out_kernel(
    const float* __restrict__ inT, const float* __restrict__ wT,
    float* __restrict__ out, int N){
  const int b = blockIdx.y, n0 = blockIdx.x*32;
  __shared__ float insh[32*129];
  const float* src = inT + ((size_t)b*N + n0)*128;
  for (int i=threadIdx.x;i<32*128;i+=256){ int nn=i>>7, c=i&127; insh[nn*129+c]=src[i]; }
  __syncthreads();
  const int nl = threadIdx.x & 31, og = threadIdx.x >> 5;
  float acc[7];
#pragma unroll
  for (int t=0;t<7;t++) acc[t]=0.f;
  for (int c=0;c<128;c++){
    float iv = insh[nl*129+c];
#pragma unroll
    for (int t=0;t<7;t++){
      int o = og + 8*t;
      float wv = (o<50)? wT[c*50+o] : 0.f;
      acc[t] = fmaf(wv, iv, acc[t]);
    }
  }
#pragma unroll
  for (int t=0;t<7;t++){
    int o = og + 8*t;
    if (o < 50) out[((size_t)b*50+o)*N + n0 + nl] = acc[t];
  }
}

extern "C" void kernel_launch(void* const* d_in, const int* in_sizes, int n_in,
                              void* d_out, int out_size, void* d_ws, size_t ws_size,
                              hipStream_t stream){
  const float* x    = (const float*)d_in[0];
  const float* l    = (const float*)d_in[1];
  const float* t_c1 = (const float*)d_in[2];
  const float* t_c2 = (const float*)d_in[3];
  const float* t_c3 = (const float*)d_in[4];
  const float* t_f1 = (const float*)d_in[5];
  const float* t_f2 = (const float*)d_in[6];
  const float* t_f3w= (const float*)d_in[7];
  const float* t_f3b= (const float*)d_in[8];
  const float* b1a  = (const float*)d_in[9];
  const float* b1b  = (const float*)d_in[10];
  const float* b2a  = (const float*)d_in[11];
  const float* b2b  = (const float*)d_in[12];
  const float* b3a  = (const float*)d_in[13];
  const float* m1   = (const float*)d_in[14];
  const float* m2   = (const float*)d_in[15];
  const float* h1   = (const float*)d_in[16];
  const float* h2   = (const float*)d_in[17];
  const float* h3   = (const float*)d_in[18];
  const float* h4   = (const float*)d_in[19];
  float* out = (float*)d_out;
  float* ws = (float*)d_ws;
  const int N = NPTS, B = BATCH;

  size_t off = 0;
  auto alloc = [&](size_t nf){ float* p = ws + off; off += nf; return p; };
  float* WT_TC3 = alloc((size_t)128*1024);
  float* WT_M1  = alloc((size_t)192*1024);
  float* WT_H1B = alloc((size_t)192*256);
  float* WT_H2  = alloc((size_t)256*256);
  float* WT_H3  = alloc((size_t)256*128);
  float* WT_H4  = alloc((size_t)128*64);
  int*   IDX    = (int*)alloc((size_t)B*N*KNN);
  float* XX     = alloc((size_t)B*N);
  float* TT     = alloc((size_t)B*N*128);
  float* PARTIAL= alloc((size_t)B*8*1024);
  float* TG     = alloc((size_t)B*1024);
  float* T512   = alloc((size_t)B*512);
  float* T256   = alloc((size_t)B*256);
  float* T9     = alloc((size_t)B*16);
  float* XP     = alloc((size_t)B*3*N);
  float* X1R    = alloc((size_t)B*64*N);
  float* X2R    = alloc((size_t)B*64*N);
  float* CATT   = alloc((size_t)B*N*192);
  float* G      = alloc((size_t)B*1024);
  float* LV     = alloc((size_t)B*64);
  float* BIAS1  = alloc((size_t)B*256);
  float* H1T    = alloc((size_t)B*N*256);
  float* H2T    = alloc((size_t)B*N*256);
  float* H3T    = alloc((size_t)B*N*128);
  (void)ws_size; (void)in_sizes; (void)n_in; (void)out_size;

  dim3 blk(256);
  // weight transposes
  transpose_kernel<<<dim3((1024*128+255)/256), blk, 0, stream>>>(t_c3, WT_TC3, 1024,128,128,0);
  transpose_kernel<<<dim3((1024*192+255)/256), blk, 0, stream>>>(m1,  WT_M1, 1024,192,192,0);
  transpose_kernel<<<dim3((256*192+255)/256),  blk, 0, stream>>>(h1, WT_H1B, 256,192,1280,1088);
  transpose_kernel<<<dim3((256*256+255)/256),  blk, 0, stream>>>(h2, WT_H2, 256,256,256,0);
  transpose_kernel<<<dim3((128*256+255)/256),  blk, 0, stream>>>(h3, WT_H3, 128,256,256,0);
  transpose_kernel<<<dim3((50*128+255)/256),   blk, 0, stream>>>(h4, WT_H4, 50,128,128,0);

  // t-path: knn on original x, edge conv, conv+max, FCs -> 3x3 transform
  norms_kernel<<<dim3(N/256,B), blk, 0, stream>>>(x, XX, 3, N);
  knn_kernel<3><<<dim3(N,B), blk, 0, stream>>>(x, nullptr, 0, 0, XX, IDX, N);
  edgeA_kernel<<<dim3(N/2,B), blk, 0, stream>>>(x, IDX, t_c1, t_c2, TT, N);
  convmax_kernel<128><<<dim3(16,8,B), blk, 0, stream>>>(TT, WT_TC3, PARTIAL, N);
  reduce_max_kernel<<<dim3(4,B), blk, 0, stream>>>(PARTIAL, TG);
  fc_kernel<<<dim3(B), dim3(512), 0, stream>>>(TG, t_f1, nullptr, T512, 1024, 512, 1);
  fc_kernel<<<dim3(B), dim3(512), 0, stream>>>(T512, t_f2, nullptr, T256, 512, 256, 1);
  fc_kernel<<<dim3(B), dim3(512), 0, stream>>>(T256, t_f3w, t_f3b, T9, 256, 9, 0);
  transform_kernel<<<dim3(N/256,B), blk, 0, stream>>>(x, T9, XP, N);

  // edge block 1 (on transformed points)
  norms_kernel<<<dim3(N/256,B), blk, 0, stream>>>(XP, XX, 3, N);
  knn_kernel<3><<<dim3(N,B), blk, 0, stream>>>(XP, nullptr, 0, 0, XX, IDX, N);
  edgeB_kernel<<<dim3(N/4,B), blk, 0, stream>>>(XP, IDX, b1a, b1b, X1R, CATT, N);

  // edge block 2 (on x1, 64ch)
  norms_kernel<<<dim3(N/256,B), blk, 0, stream>>>(X1R, XX, 64, N);
  knn_kernel<64><<<dim3(N,B), blk, 0, stream>>>(X1R, CATT, 192, 0, XX, IDX, N);
  edgeC_kernel<<<dim3(N/4,B), blk, 0, stream>>>(CATT, 0, IDX, b2a, b2b, X2R, CATT, 64, N);

  // edge block 3 (on x2, 64ch, single conv)
  norms_kernel<<<dim3(N/256,B), blk, 0, stream>>>(X2R, XX, 64, N);
  knn_kernel<64><<<dim3(N,B), blk, 0, stream>>>(X2R, CATT, 192, 64, XX, IDX, N);
  edgeD_kernel<<<dim3(N/4,B), blk, 0, stream>>>(CATT, 64, IDX, b3a, CATT, 128, N);

  // global feature + label vector + head
  convmax_kernel<192><<<dim3(16,8,B), blk, 0, stream>>>(CATT, WT_M1, PARTIAL, N);
  reduce_max_kernel<<<dim3(4,B), blk, 0, stream>>>(PARTIAL, G);
  fc_kernel<<<dim3(B), dim3(512), 0, stream>>>(l, m2, nullptr, LV, 16, 64, 1);
  bias1_kernel<<<dim3(B), blk, 0, stream>>>(G, LV, h1, BIAS1);
  conv1_kernel<192,256,true><<<dim3(N/32,B), blk, 0, stream>>>(CATT, WT_H1B, BIAS1, H1T, N);
  conv1_kernel<256,256,true><<<dim3(N/32,B), blk, 0, stream>>>(H1T, WT_H2, nullptr, H2T, N);
  conv1_kernel<256,128,true><<<dim3(N/32,B), blk, 0, stream>>>(H2T, WT_H3, nullptr, H3T, N);
  conv_out_kernel<<<dim3(N/32,B), blk, 0, stream>>>(H3T, WT_H4, out, N);
}